// Round 6
// baseline (430.333 us; speedup 1.0000x reference)
//
#include <hip/hip_runtime.h>
#include <hip/hip_bf16.h>

#define NUM_C 1000
#define DIM   128
#define MM    64
#define BB    64
#define LL    512
#define NROWS (BB * LL)   // 32768

__device__ __forceinline__ float sigmoidf_fast(float x) { return 1.f / (1.f + __expf(-x)); }
__device__ __forceinline__ float tanhf_fast(float x) { return 1.f - 2.f / (__expf(2.f * x) + 1.f); }

// DPP quad_perm(1,0,3,2): swap neighbor pairs within each quad
__device__ __forceinline__ float quad_swap1(float x) {
    return __int_as_float(__builtin_amdgcn_mov_dpp(__float_as_int(x), 0xB1, 0xF, 0xF, true));
}
// DPP quad_perm(2,3,0,1): swap halves within each quad
__device__ __forceinline__ float quad_swap2(float x) {
    return __int_as_float(__builtin_amdgcn_mov_dpp(__float_as_int(x), 0x4E, 0xF, 0xF, true));
}

__device__ __forceinline__ float dot4(float4 a, float4 b, float acc) {
    return fmaf(a.x, b.x, fmaf(a.y, b.y, fmaf(a.z, b.z, fmaf(a.w, b.w, acc))));
}

// ---------------------------------------------------------------------------
// Kernel A: w[b,l,m] = softmax_m( k . Mk[m] ),  k = Ek[q[b,l]]
// 256 threads = 4 waves; each wave computes 4 rows; lane = m.
// Mk in LDS as float4 [i4][m]; k rows via wave-uniform (scalar) loads.
// ---------------------------------------------------------------------------
__global__ __launch_bounds__(256) void kA(const int* __restrict__ q,
                                          const float* __restrict__ Ek,
                                          const float* __restrict__ Mk,
                                          float* __restrict__ w_out) {
    __shared__ __align__(16) float4 Mk4[32][64];   // 32 KB
    const int tid = threadIdx.x;
    const int lane = tid & 63;
    const int wv = tid >> 6;

    #pragma unroll
    for (int j = 0; j < 8; ++j) {
        int i4 = wv + 4 * j;
        Mk4[i4][lane] = *reinterpret_cast<const float4*>(Mk + lane * DIM + i4 * 4);
    }
    __syncthreads();

    const int rb = __builtin_amdgcn_readfirstlane(blockIdx.x * 16 + wv * 4);
    const float* k0 = Ek + (size_t)q[rb + 0] * DIM;
    const float* k1 = Ek + (size_t)q[rb + 1] * DIM;
    const float* k2 = Ek + (size_t)q[rb + 2] * DIM;
    const float* k3 = Ek + (size_t)q[rb + 3] * DIM;

    float acc[4] = {0.f, 0.f, 0.f, 0.f};
    #pragma unroll 8
    for (int i4 = 0; i4 < 32; ++i4) {
        float4 mk = Mk4[i4][lane];
        float4 a0 = *reinterpret_cast<const float4*>(k0 + i4 * 4);
        float4 a1 = *reinterpret_cast<const float4*>(k1 + i4 * 4);
        float4 a2 = *reinterpret_cast<const float4*>(k2 + i4 * 4);
        float4 a3 = *reinterpret_cast<const float4*>(k3 + i4 * 4);
        acc[0] = dot4(a0, mk, acc[0]);
        acc[1] = dot4(a1, mk, acc[1]);
        acc[2] = dot4(a2, mk, acc[2]);
        acc[3] = dot4(a3, mk, acc[3]);
    }

    #pragma unroll
    for (int rr = 0; rr < 4; ++rr) {
        float s = acc[rr];
        float mx = s;
        #pragma unroll
        for (int o = 32; o >= 1; o >>= 1) mx = fmaxf(mx, __shfl_xor(mx, o));
        float ex = __expf(s - mx);
        float sum = ex;
        #pragma unroll
        for (int o = 32; o >= 1; o >>= 1) sum += __shfl_xor(sum, o);
        w_out[(size_t)(rb + rr) * MM + lane] = ex / sum;
    }
}

// ---------------------------------------------------------------------------
// Kernel B: e = sigmoid(v@We+be), a = tanh(v@Wa+ba),  v = Ev[q+1000*r]
// 128 threads, 16 rows per block; depth-8 register ring on We/Wa loads.
// ---------------------------------------------------------------------------
__global__ __launch_bounds__(128) void kB(const int* __restrict__ q,
                                          const int* __restrict__ r,
                                          const float* __restrict__ Ev,
                                          const float* __restrict__ We,
                                          const float* __restrict__ be,
                                          const float* __restrict__ Wa,
                                          const float* __restrict__ ba,
                                          float* __restrict__ e_out,
                                          float* __restrict__ a_out) {
    __shared__ __align__(16) float vbufT[DIM][20];
    const int tid = threadIdx.x;
    const int base = blockIdx.x * 16;

    #pragma unroll
    for (int rr = 0; rr < 16; ++rr) {
        int row = base + rr;
        int x = q[row] + NUM_C * r[row];
        vbufT[tid][rr] = Ev[(size_t)x * DIM + tid];
    }
    __syncthreads();

    float eacc[16], aacc[16];
    #pragma unroll
    for (int rr = 0; rr < 16; ++rr) { eacc[rr] = 0.f; aacc[rr] = 0.f; }

    float weR[8], waR[8];
    #pragma unroll
    for (int u = 0; u < 8; ++u) {
        weR[u] = We[u * DIM + tid];
        waR[u] = Wa[u * DIM + tid];
    }

    #pragma unroll 8
    for (int i = 0; i < DIM; ++i) {
        float we = weR[i & 7];
        float wa = waR[i & 7];
        if (i + 8 < DIM) {
            weR[i & 7] = We[(i + 8) * DIM + tid];
            waR[i & 7] = Wa[(i + 8) * DIM + tid];
        }
        const float4* vp = reinterpret_cast<const float4*>(&vbufT[i][0]);
        float4 v0 = vp[0], v1 = vp[1], v2 = vp[2], v3 = vp[3];
        float vr[16] = {v0.x, v0.y, v0.z, v0.w, v1.x, v1.y, v1.z, v1.w,
                        v2.x, v2.y, v2.z, v2.w, v3.x, v3.y, v3.z, v3.w};
        #pragma unroll
        for (int rr = 0; rr < 16; ++rr) {
            eacc[rr] = fmaf(vr[rr], we, eacc[rr]);
            aacc[rr] = fmaf(vr[rr], wa, aacc[rr]);
        }
    }

    float bev = be[tid], bav = ba[tid];
    #pragma unroll
    for (int rr = 0; rr < 16; ++rr) {
        int row = base + rr;
        e_out[(size_t)row * DIM + tid] = sigmoidf_fast(eacc[rr] + bev);
        a_out[(size_t)row * DIM + tid] = tanhf_fast(aacc[rr] + bav);
    }
}

// ---------------------------------------------------------------------------
// Kernel C: all-register scan, 2x TLP. Grid (g=4, ds=2, b=64) = 512 blocks.
// 256 threads: p = tid&3 (4 lanes per d, each owns 4 m), dl = tid>>2,
// d = ds*64+dl. e/a: 16-step register tiles double-buffered; w: depth-8
// float4 ring. Quad butterfly reduce, plain stores to per-g partial.
// ---------------------------------------------------------------------------
__device__ __forceinline__ void kc_load_tile(const float* ep, const float* ap,
                                             int c, float (&eR)[16], float (&aR)[16]) {
    if (c < LL / 16) {
        #pragma unroll
        for (int u = 0; u < 16; ++u) {
            eR[u] = ep[(size_t)(c * 16 + u) * DIM];
            aR[u] = ap[(size_t)(c * 16 + u) * DIM];
        }
    }
}

__device__ __forceinline__ void kc_scan_tile(int c, int p, float (&Mv)[4],
                                             const float (&eR)[16], const float (&aR)[16],
                                             float4 (&wR)[8],
                                             const float* wp, float* pr) {
    #pragma unroll
    for (int u = 0; u < 16; ++u) {
        const int t = c * 16 + u;
        const int slot = u & 7;                 // (c*16)&7==0 -> compile-time
        float4 w4 = wR[slot];
        if (t + 8 < LL)                         // prefetch w for t+8
            wR[slot] = *reinterpret_cast<const float4*>(wp + (size_t)(t + 8) * MM);
        float e_c = eR[u], a_c = aR[u];
        float wv[4] = {w4.x, w4.y, w4.z, w4.w};
        float part = 0.f;
        #pragma unroll
        for (int j = 0; j < 4; ++j) {
            float old = Mv[j];
            part = fmaf(wv[j], old, part);             // read BEFORE update
            Mv[j] = fmaf(wv[j], fmaf(-old, e_c, a_c), old);
        }
        part += quad_swap1(part);
        part += quad_swap2(part);
        if (p == 0) pr[(size_t)t * DIM] = part;
    }
}

__global__ __launch_bounds__(256) void kC(const float* __restrict__ Mv0,
                                          const float* __restrict__ w_in,
                                          const float* __restrict__ e_in,
                                          const float* __restrict__ a_in,
                                          float* __restrict__ partial) {
    const int tid = threadIdx.x;
    const int p = tid & 3;
    const int dl = tid >> 2;
    const int g = blockIdx.x, ds = blockIdx.y, b = blockIdx.z;
    const int d = ds * 64 + dl;
    const int m0 = g * 16 + p * 4;

    float Mv[4];
    #pragma unroll
    for (int j = 0; j < 4; ++j)
        Mv[j] = Mv0[(m0 + j) * DIM + d];

    const float* wp = w_in + (size_t)b * LL * MM + m0;
    const float* ep = e_in + (size_t)b * LL * DIM + d;
    const float* ap = a_in + (size_t)b * LL * DIM + d;
    float* pr = partial + ((size_t)(g * BB + b) * LL) * DIM + d;

    float eR0[16], aR0[16], eR1[16], aR1[16];
    float4 wR[8];

    kc_load_tile(ep, ap, 0, eR0, aR0);
    #pragma unroll
    for (int u = 0; u < 8; ++u)
        wR[u] = *reinterpret_cast<const float4*>(wp + (size_t)u * MM);

    for (int c = 0; c < LL / 16; c += 2) {
        kc_load_tile(ep, ap, c + 1, eR1, aR1);   // next tile in flight
        kc_scan_tile(c, p, Mv, eR0, aR0, wR, wp, pr);
        kc_load_tile(ep, ap, c + 2, eR0, aR0);
        kc_scan_tile(c + 1, p, Mv, eR1, aR1, wR, wp, pr);
    }
}

// ---------------------------------------------------------------------------
// Kernel D: read = sum_g partial; f = tanh([read,k]@Wf + bf); p = sigmoid(f@Wp+bp)
// 128 threads, 16 rows/block; depth-8 register ring on Wf; shuffle-reduce
// epilogue (no fbuf -> 20 KB LDS, ~7 blocks/CU).
// ---------------------------------------------------------------------------
__global__ __launch_bounds__(128) void kD(const int* __restrict__ q,
                                          const float* __restrict__ Ek,
                                          const float* __restrict__ Wf,
                                          const float* __restrict__ bfv,
                                          const float* __restrict__ Wp,
                                          const float* __restrict__ bp,
                                          const float* __restrict__ partial,
                                          float* __restrict__ out) {
    __shared__ __align__(16) float xbufT[2 * DIM][20];
    __shared__ float sred[16][2];
    const int tid = threadIdx.x;
    const int lane = tid & 63;
    const int wv = tid >> 6;
    const int base = blockIdx.x * 16;

    #pragma unroll
    for (int rr = 0; rr < 16; ++rr) {
        int row = base + rr;
        float rd = 0.f;
        #pragma unroll
        for (int g = 0; g < 4; ++g)
            rd += partial[(size_t)g * NROWS * DIM + (size_t)row * DIM + tid];
        xbufT[tid][rr] = rd;
        xbufT[DIM + tid][rr] = Ek[(size_t)q[row] * DIM + tid];
    }
    __syncthreads();

    float facc[16];
    #pragma unroll
    for (int rr = 0; rr < 16; ++rr) facc[rr] = 0.f;

    float wfR[8];
    #pragma unroll
    for (int u = 0; u < 8; ++u) wfR[u] = Wf[u * DIM + tid];

    #pragma unroll 8
    for (int i = 0; i < 2 * DIM; ++i) {
        float wf = wfR[i & 7];
        if (i + 8 < 2 * DIM) wfR[i & 7] = Wf[(i + 8) * DIM + tid];
        const float4* xp = reinterpret_cast<const float4*>(&xbufT[i][0]);
        float4 x0 = xp[0], x1 = xp[1], x2 = xp[2], x3 = xp[3];
        float xr[16] = {x0.x, x0.y, x0.z, x0.w, x1.x, x1.y, x1.z, x1.w,
                        x2.x, x2.y, x2.z, x2.w, x3.x, x3.y, x3.z, x3.w};
        #pragma unroll
        for (int rr = 0; rr < 16; ++rr)
            facc[rr] = fmaf(xr[rr], wf, facc[rr]);
    }

    float bfs = bfv[tid];
    float wpv = Wp[tid];
    #pragma unroll
    for (int rr = 0; rr < 16; ++rr) {
        float t = tanhf_fast(facc[rr] + bfs) * wpv;
        #pragma unroll
        for (int o = 32; o >= 1; o >>= 1) t += __shfl_xor(t, o);
        if (lane == 0) sred[rr][wv] = t;
    }
    __syncthreads();
    if (tid < 16)
        out[base + tid] = sigmoidf_fast(sred[tid][0] + sred[tid][1] + bp[0]);
}

// ---------------------------------------------------------------------------
extern "C" void kernel_launch(void* const* d_in, const int* in_sizes, int n_in,
                              void* d_out, int out_size, void* d_ws, size_t ws_size,
                              hipStream_t stream) {
    const int*   q   = (const int*)d_in[0];
    const int*   r   = (const int*)d_in[1];
    const float* Ek  = (const float*)d_in[2];
    const float* Ev  = (const float*)d_in[3];
    const float* Mk  = (const float*)d_in[4];
    const float* Mv0 = (const float*)d_in[5];
    const float* We  = (const float*)d_in[6];
    const float* be  = (const float*)d_in[7];
    const float* Wa  = (const float*)d_in[8];
    const float* ba  = (const float*)d_in[9];
    const float* Wf  = (const float*)d_in[10];
    const float* bfv = (const float*)d_in[11];
    const float* Wp  = (const float*)d_in[12];
    const float* bp  = (const float*)d_in[13];
    float* out = (float*)d_out;

    float* ws    = (float*)d_ws;
    float* w_buf = ws;                                   // 8 MB
    float* e_buf = w_buf + (size_t)NROWS * MM;           // 16 MB
    float* a_buf = e_buf + (size_t)NROWS * DIM;          // 16 MB
    float* part  = a_buf + (size_t)NROWS * DIM;          // 4 x 16 MB

    kA<<<dim3(NROWS / 16), 256, 0, stream>>>(q, Ek, Mk, w_buf);
    kB<<<dim3(NROWS / 16), 128, 0, stream>>>(q, r, Ev, We, be, Wa, ba, e_buf, a_buf);
    kC<<<dim3(4, 2, BB), 256, 0, stream>>>(Mv0, w_buf, e_buf, a_buf, part);
    kD<<<dim3(NROWS / 16), 128, 0, stream>>>(q, Ek, Wf, bfv, Wp, bp, part, out);
}

// Round 7
// 359.250 us; speedup vs baseline: 1.1979x; 1.1979x over previous
//
#include <hip/hip_runtime.h>
#include <hip/hip_bf16.h>

#define NUM_C 1000
#define DIM   128
#define MM    64
#define BB    64
#define LL    512
#define NROWS (BB * LL)   // 32768

__device__ __forceinline__ float sigmoidf_fast(float x) { return 1.f / (1.f + __expf(-x)); }
__device__ __forceinline__ float tanhf_fast(float x) { return 1.f - 2.f / (__expf(2.f * x) + 1.f); }

// DPP quad_perm(1,0,3,2): swap neighbor pairs within each quad
__device__ __forceinline__ float quad_swap1(float x) {
    return __int_as_float(__builtin_amdgcn_mov_dpp(__float_as_int(x), 0xB1, 0xF, 0xF, true));
}
// DPP quad_perm(2,3,0,1): swap halves within each quad
__device__ __forceinline__ float quad_swap2(float x) {
    return __int_as_float(__builtin_amdgcn_mov_dpp(__float_as_int(x), 0x4E, 0xF, 0xF, true));
}

__device__ __forceinline__ float dot4(float4 a, float4 b, float acc) {
    return fmaf(a.x, b.x, fmaf(a.y, b.y, fmaf(a.z, b.z, fmaf(a.w, b.w, acc))));
}

// ---------------------------------------------------------------------------
// Kernel A: w[b,l,m] = softmax_m( k . Mk[m] ),  k = Ek[q[b,l]]
// 256 threads = 4 waves; each wave computes 4 rows; lane = m.
// ---------------------------------------------------------------------------
__global__ __launch_bounds__(256) void kA(const int* __restrict__ q,
                                          const float* __restrict__ Ek,
                                          const float* __restrict__ Mk,
                                          float* __restrict__ w_out) {
    __shared__ __align__(16) float4 Mk4[32][64];   // 32 KB
    const int tid = threadIdx.x;
    const int lane = tid & 63;
    const int wv = tid >> 6;

    #pragma unroll
    for (int j = 0; j < 8; ++j) {
        int i4 = wv + 4 * j;
        Mk4[i4][lane] = *reinterpret_cast<const float4*>(Mk + lane * DIM + i4 * 4);
    }
    __syncthreads();

    const int rb = __builtin_amdgcn_readfirstlane(blockIdx.x * 16 + wv * 4);
    const float* k0 = Ek + (size_t)q[rb + 0] * DIM;
    const float* k1 = Ek + (size_t)q[rb + 1] * DIM;
    const float* k2 = Ek + (size_t)q[rb + 2] * DIM;
    const float* k3 = Ek + (size_t)q[rb + 3] * DIM;

    float acc[4] = {0.f, 0.f, 0.f, 0.f};
    #pragma unroll 8
    for (int i4 = 0; i4 < 32; ++i4) {
        float4 mk = Mk4[i4][lane];
        float4 a0 = *reinterpret_cast<const float4*>(k0 + i4 * 4);
        float4 a1 = *reinterpret_cast<const float4*>(k1 + i4 * 4);
        float4 a2 = *reinterpret_cast<const float4*>(k2 + i4 * 4);
        float4 a3 = *reinterpret_cast<const float4*>(k3 + i4 * 4);
        acc[0] = dot4(a0, mk, acc[0]);
        acc[1] = dot4(a1, mk, acc[1]);
        acc[2] = dot4(a2, mk, acc[2]);
        acc[3] = dot4(a3, mk, acc[3]);
    }

    #pragma unroll
    for (int rr = 0; rr < 4; ++rr) {
        float s = acc[rr];
        float mx = s;
        #pragma unroll
        for (int o = 32; o >= 1; o >>= 1) mx = fmaxf(mx, __shfl_xor(mx, o));
        float ex = __expf(s - mx);
        float sum = ex;
        #pragma unroll
        for (int o = 32; o >= 1; o >>= 1) sum += __shfl_xor(sum, o);
        w_out[(size_t)(rb + rr) * MM + lane] = ex / sum;
    }
}

// ---------------------------------------------------------------------------
// Kernel B: e = sigmoid(v@We+be), a = tanh(v@Wa+ba),  v = Ev[q+1000*r]
// 512 threads, 16 rows/block. Group h=tid>>7: h<2 -> We (i-half h),
// h>=2 -> Wa (i-half h-2). Weight slice (64 floats) PRE-REGISTERED in bulk;
// inner loop = uniform LDS broadcasts + FMA only. One-barrier slab reduce.
// ---------------------------------------------------------------------------
__global__ __launch_bounds__(512) void kB(const int* __restrict__ q,
                                          const int* __restrict__ r,
                                          const float* __restrict__ Ev,
                                          const float* __restrict__ We,
                                          const float* __restrict__ be,
                                          const float* __restrict__ Wa,
                                          const float* __restrict__ ba,
                                          float* __restrict__ e_out,
                                          float* __restrict__ a_out) {
    __shared__ __align__(16) float vbufT[DIM][20];     // 10 KB
    __shared__ float slab[4][16][DIM];                 // 32 KB
    const int tid = threadIdx.x;
    const int dout = tid & 127;
    const int h = tid >> 7;            // 0..3, wave-uniform
    const int ihalf = h & 1;
    const int base = blockIdx.x * 16;

    // stage v transposed: group h stages rows [4h, 4h+4)
    #pragma unroll
    for (int rr = 0; rr < 4; ++rr) {
        int row = base + h * 4 + rr;
        int x = q[row] + NUM_C * r[row];
        vbufT[dout][h * 4 + rr] = Ev[(size_t)x * DIM + dout];
    }

    // bulk weight preload: 64 floats/thread, all in flight at once
    const float* W = (h >= 2) ? Wa : We;
    float wreg[64];
    #pragma unroll
    for (int j = 0; j < 64; ++j)
        wreg[j] = W[(ihalf * 64 + j) * DIM + dout];

    __syncthreads();   // vbufT ready

    float acc[16];
    #pragma unroll
    for (int rr = 0; rr < 16; ++rr) acc[rr] = 0.f;

    #pragma unroll 4
    for (int j = 0; j < 64; ++j) {
        const int i = ihalf * 64 + j;
        const float4* vp = reinterpret_cast<const float4*>(&vbufT[i][0]);
        float4 v0 = vp[0], v1 = vp[1], v2 = vp[2], v3 = vp[3];
        float vr[16] = {v0.x, v0.y, v0.z, v0.w, v1.x, v1.y, v1.z, v1.w,
                        v2.x, v2.y, v2.z, v2.w, v3.x, v3.y, v3.z, v3.w};
        float wv = wreg[j];
        #pragma unroll
        for (int rr = 0; rr < 16; ++rr)
            acc[rr] = fmaf(vr[rr], wv, acc[rr]);
    }

    #pragma unroll
    for (int rr = 0; rr < 16; ++rr) slab[h][rr][dout] = acc[rr];
    __syncthreads();

    if (h == 0) {          // e = sigmoid(We-halves + be)
        float bev = be[dout];
        #pragma unroll
        for (int rr = 0; rr < 16; ++rr) {
            int row = base + rr;
            float s = slab[0][rr][dout] + slab[1][rr][dout] + bev;
            e_out[(size_t)row * DIM + dout] = sigmoidf_fast(s);
        }
    } else if (h == 1) {   // a = tanh(Wa-halves + ba)
        float bav = ba[dout];
        #pragma unroll
        for (int rr = 0; rr < 16; ++rr) {
            int row = base + rr;
            float s = slab[2][rr][dout] + slab[3][rr][dout] + bav;
            a_out[(size_t)row * DIM + dout] = tanhf_fast(s);
        }
    }
}

// ---------------------------------------------------------------------------
// Kernel C: all-register scan, 2x TLP. Grid (g=4, ds=2, b=64) = 512 blocks.
// 256 threads: p = tid&3 (4 lanes per d, 4 m each), d = ds*64 + (tid>>2).
// e/a: 16-step register tiles double-buffered; w: depth-8 float4 ring.
// ---------------------------------------------------------------------------
__device__ __forceinline__ void kc_load_tile(const float* ep, const float* ap,
                                             int c, float (&eR)[16], float (&aR)[16]) {
    if (c < LL / 16) {
        #pragma unroll
        for (int u = 0; u < 16; ++u) {
            eR[u] = ep[(size_t)(c * 16 + u) * DIM];
            aR[u] = ap[(size_t)(c * 16 + u) * DIM];
        }
    }
}

__device__ __forceinline__ void kc_scan_tile(int c, int p, float (&Mv)[4],
                                             const float (&eR)[16], const float (&aR)[16],
                                             float4 (&wR)[8],
                                             const float* wp, float* pr) {
    #pragma unroll
    for (int u = 0; u < 16; ++u) {
        const int t = c * 16 + u;
        const int slot = u & 7;
        float4 w4 = wR[slot];
        if (t + 8 < LL)
            wR[slot] = *reinterpret_cast<const float4*>(wp + (size_t)(t + 8) * MM);
        float e_c = eR[u], a_c = aR[u];
        float wv[4] = {w4.x, w4.y, w4.z, w4.w};
        float part = 0.f;
        #pragma unroll
        for (int j = 0; j < 4; ++j) {
            float old = Mv[j];
            part = fmaf(wv[j], old, part);             // read BEFORE update
            Mv[j] = fmaf(wv[j], fmaf(-old, e_c, a_c), old);
        }
        part += quad_swap1(part);
        part += quad_swap2(part);
        if (p == 0) pr[(size_t)t * DIM] = part;
    }
}

__global__ __launch_bounds__(256) void kC(const float* __restrict__ Mv0,
                                          const float* __restrict__ w_in,
                                          const float* __restrict__ e_in,
                                          const float* __restrict__ a_in,
                                          float* __restrict__ partial) {
    const int tid = threadIdx.x;
    const int p = tid & 3;
    const int dl = tid >> 2;
    const int g = blockIdx.x, ds = blockIdx.y, b = blockIdx.z;
    const int d = ds * 64 + dl;
    const int m0 = g * 16 + p * 4;

    float Mv[4];
    #pragma unroll
    for (int j = 0; j < 4; ++j)
        Mv[j] = Mv0[(m0 + j) * DIM + d];

    const float* wp = w_in + (size_t)b * LL * MM + m0;
    const float* ep = e_in + (size_t)b * LL * DIM + d;
    const float* ap = a_in + (size_t)b * LL * DIM + d;
    float* pr = partial + ((size_t)(g * BB + b) * LL) * DIM + d;

    float eR0[16], aR0[16], eR1[16], aR1[16];
    float4 wR[8];

    kc_load_tile(ep, ap, 0, eR0, aR0);
    #pragma unroll
    for (int u = 0; u < 8; ++u)
        wR[u] = *reinterpret_cast<const float4*>(wp + (size_t)u * MM);

    for (int c = 0; c < LL / 16; c += 2) {
        kc_load_tile(ep, ap, c + 1, eR1, aR1);
        kc_scan_tile(c, p, Mv, eR0, aR0, wR, wp, pr);
        kc_load_tile(ep, ap, c + 2, eR0, aR0);
        kc_scan_tile(c + 1, p, Mv, eR1, aR1, wR, wp, pr);
    }
}

// ---------------------------------------------------------------------------
// Kernel D: read = sum_g partial; f = tanh([read,k]@Wf + bf); p = sigmoid(f@Wp+bp)
// 512 threads, 16 rows/block. Group h=tid>>7 owns i-quarter [64h, 64h+64);
// Wf slice (64 floats) pre-registered. Slab reduce + LDS-tree dot with Wp.
// ---------------------------------------------------------------------------
__global__ __launch_bounds__(512) void kD(const int* __restrict__ q,
                                          const float* __restrict__ Ek,
                                          const float* __restrict__ Wf,
                                          const float* __restrict__ bfv,
                                          const float* __restrict__ Wp,
                                          const float* __restrict__ bp,
                                          const float* __restrict__ partial,
                                          float* __restrict__ out) {
    __shared__ __align__(16) float xbufT[2 * DIM][20];  // 20 KB
    __shared__ float slab[4][16][DIM];                  // 32 KB
    __shared__ float sbuf[16][8];
    const int tid = threadIdx.x;
    const int dout = tid & 127;
    const int h = tid >> 7;            // 0..3, wave-uniform
    const int base = blockIdx.x * 16;

    // stage x = [read | k] transposed: group h stages rows [4h, 4h+4)
    #pragma unroll
    for (int rr = 0; rr < 4; ++rr) {
        int row = base + h * 4 + rr;
        float rd = 0.f;
        #pragma unroll
        for (int g = 0; g < 4; ++g)
            rd += partial[(size_t)g * NROWS * DIM + (size_t)row * DIM + dout];
        xbufT[dout][h * 4 + rr] = rd;
        xbufT[DIM + dout][h * 4 + rr] = Ek[(size_t)q[row] * DIM + dout];
    }

    // bulk weight preload: 64 floats/thread (i-quarter), all in flight
    float wreg[64];
    #pragma unroll
    for (int j = 0; j < 64; ++j)
        wreg[j] = Wf[(h * 64 + j) * DIM + dout];

    __syncthreads();   // xbufT ready

    float facc[16];
    #pragma unroll
    for (int rr = 0; rr < 16; ++rr) facc[rr] = 0.f;

    #pragma unroll 4
    for (int j = 0; j < 64; ++j) {
        const int i = h * 64 + j;
        const float4* xp = reinterpret_cast<const float4*>(&xbufT[i][0]);
        float4 x0 = xp[0], x1 = xp[1], x2 = xp[2], x3 = xp[3];
        float xr[16] = {x0.x, x0.y, x0.z, x0.w, x1.x, x1.y, x1.z, x1.w,
                        x2.x, x2.y, x2.z, x2.w, x3.x, x3.y, x3.z, x3.w};
        float wv = wreg[j];
        #pragma unroll
        for (int rr = 0; rr < 16; ++rr)
            facc[rr] = fmaf(xr[rr], wv, facc[rr]);
    }

    #pragma unroll
    for (int rr = 0; rr < 16; ++rr) slab[h][rr][dout] = facc[rr];
    __syncthreads();

    if (h == 0) {   // finish f, multiply by Wp, stash t back into slab[0]
        float bfs = bfv[dout];
        float wpv = Wp[dout];
        #pragma unroll
        for (int rr = 0; rr < 16; ++rr) {
            float fsum = slab[0][rr][dout] + slab[1][rr][dout]
                       + slab[2][rr][dout] + slab[3][rr][dout] + bfs;
            slab[0][rr][dout] = tanhf_fast(fsum) * wpv;
        }
    }
    __syncthreads();

    if (tid < 128) {
        int rr = tid >> 3, j = tid & 7;
        float s = 0.f;
        #pragma unroll
        for (int i = 0; i < 16; ++i) s += slab[0][rr][j + 8 * i];
        sbuf[rr][j] = s;
    }
    __syncthreads();
    if (tid < 16) {
        float s = bp[0];
        #pragma unroll
        for (int j = 0; j < 8; ++j) s += sbuf[tid][j];
        out[base + tid] = sigmoidf_fast(s);
    }
}

// ---------------------------------------------------------------------------
extern "C" void kernel_launch(void* const* d_in, const int* in_sizes, int n_in,
                              void* d_out, int out_size, void* d_ws, size_t ws_size,
                              hipStream_t stream) {
    const int*   q   = (const int*)d_in[0];
    const int*   r   = (const int*)d_in[1];
    const float* Ek  = (const float*)d_in[2];
    const float* Ev  = (const float*)d_in[3];
    const float* Mk  = (const float*)d_in[4];
    const float* Mv0 = (const float*)d_in[5];
    const float* We  = (const float*)d_in[6];
    const float* be  = (const float*)d_in[7];
    const float* Wa  = (const float*)d_in[8];
    const float* ba  = (const float*)d_in[9];
    const float* Wf  = (const float*)d_in[10];
    const float* bfv = (const float*)d_in[11];
    const float* Wp  = (const float*)d_in[12];
    const float* bp  = (const float*)d_in[13];
    float* out = (float*)d_out;

    float* ws    = (float*)d_ws;
    float* w_buf = ws;                                   // 8 MB
    float* e_buf = w_buf + (size_t)NROWS * MM;           // 16 MB
    float* a_buf = e_buf + (size_t)NROWS * DIM;          // 16 MB
    float* part  = a_buf + (size_t)NROWS * DIM;          // 4 x 16 MB

    kA<<<dim3(NROWS / 16), 256, 0, stream>>>(q, Ek, Mk, w_buf);
    kB<<<dim3(NROWS / 16), 512, 0, stream>>>(q, r, Ev, We, be, Wa, ba, e_buf, a_buf);
    kC<<<dim3(4, 2, BB), 256, 0, stream>>>(Mv0, w_buf, e_buf, a_buf, part);
    kD<<<dim3(NROWS / 16), 512, 0, stream>>>(q, Ek, Wf, bfv, Wp, bp, part, out);
}

// Round 8
// 275.037 us; speedup vs baseline: 1.5646x; 1.3062x over previous
//
#include <hip/hip_runtime.h>
#include <hip/hip_bf16.h>

#define NUM_C 1000
#define DIM   128
#define MM    64
#define BB    64
#define LL    512
#define NROWS (BB * LL)   // 32768

__device__ __forceinline__ float sigmoidf_fast(float x) { return 1.f / (1.f + __expf(-x)); }
__device__ __forceinline__ float tanhf_fast(float x) { return 1.f - 2.f / (__expf(2.f * x) + 1.f); }

// DPP quad_perm(1,0,3,2): swap neighbor pairs within each quad
__device__ __forceinline__ float quad_swap1(float x) {
    return __int_as_float(__builtin_amdgcn_mov_dpp(__float_as_int(x), 0xB1, 0xF, 0xF, true));
}
// DPP quad_perm(2,3,0,1): swap halves within each quad
__device__ __forceinline__ float quad_swap2(float x) {
    return __int_as_float(__builtin_amdgcn_mov_dpp(__float_as_int(x), 0x4E, 0xF, 0xF, true));
}

__device__ __forceinline__ float dot4(float4 a, float4 b, float acc) {
    return fmaf(a.x, b.x, fmaf(a.y, b.y, fmaf(a.z, b.z, fmaf(a.w, b.w, acc))));
}

// ---------------------------------------------------------------------------
// Kernel A: w[b,l,m] = softmax_m( k . Mk[m] ),  k = Ek[q[b,l]]
// 256 threads = 4 waves; each wave computes 4 rows; lane = m.
// ---------------------------------------------------------------------------
__global__ __launch_bounds__(256) void kA(const int* __restrict__ q,
                                          const float* __restrict__ Ek,
                                          const float* __restrict__ Mk,
                                          float* __restrict__ w_out) {
    __shared__ __align__(16) float4 Mk4[32][64];   // 32 KB
    const int tid = threadIdx.x;
    const int lane = tid & 63;
    const int wv = tid >> 6;

    #pragma unroll
    for (int j = 0; j < 8; ++j) {
        int i4 = wv + 4 * j;
        Mk4[i4][lane] = *reinterpret_cast<const float4*>(Mk + lane * DIM + i4 * 4);
    }
    __syncthreads();

    const int rb = __builtin_amdgcn_readfirstlane(blockIdx.x * 16 + wv * 4);
    const float* k0 = Ek + (size_t)q[rb + 0] * DIM;
    const float* k1 = Ek + (size_t)q[rb + 1] * DIM;
    const float* k2 = Ek + (size_t)q[rb + 2] * DIM;
    const float* k3 = Ek + (size_t)q[rb + 3] * DIM;

    float acc[4] = {0.f, 0.f, 0.f, 0.f};
    #pragma unroll 8
    for (int i4 = 0; i4 < 32; ++i4) {
        float4 mk = Mk4[i4][lane];
        float4 a0 = *reinterpret_cast<const float4*>(k0 + i4 * 4);
        float4 a1 = *reinterpret_cast<const float4*>(k1 + i4 * 4);
        float4 a2 = *reinterpret_cast<const float4*>(k2 + i4 * 4);
        float4 a3 = *reinterpret_cast<const float4*>(k3 + i4 * 4);
        acc[0] = dot4(a0, mk, acc[0]);
        acc[1] = dot4(a1, mk, acc[1]);
        acc[2] = dot4(a2, mk, acc[2]);
        acc[3] = dot4(a3, mk, acc[3]);
    }

    #pragma unroll
    for (int rr = 0; rr < 4; ++rr) {
        float s = acc[rr];
        float mx = s;
        #pragma unroll
        for (int o = 32; o >= 1; o >>= 1) mx = fmaxf(mx, __shfl_xor(mx, o));
        float ex = __expf(s - mx);
        float sum = ex;
        #pragma unroll
        for (int o = 32; o >= 1; o >>= 1) sum += __shfl_xor(sum, o);
        w_out[(size_t)(rb + rr) * MM + lane] = ex / sum;
    }
}

// ---------------------------------------------------------------------------
// Kernel B: e = sigmoid(v@We+be), a = tanh(v@Wa+ba),  v = Ev[q+1000*r]
// 512 threads, 16 rows/block. Group h=tid>>7: h<2 -> We (i-half h),
// h>=2 -> Wa (i-half h-2). Weight slice (64 floats) in registers —
// j-loop FULLY unrolled so wreg indices are compile-time (no scratch).
// ---------------------------------------------------------------------------
__global__ __launch_bounds__(512) void kB(const int* __restrict__ q,
                                          const int* __restrict__ r,
                                          const float* __restrict__ Ev,
                                          const float* __restrict__ We,
                                          const float* __restrict__ be,
                                          const float* __restrict__ Wa,
                                          const float* __restrict__ ba,
                                          float* __restrict__ e_out,
                                          float* __restrict__ a_out) {
    __shared__ __align__(16) float vbufT[DIM][20];     // 10 KB
    __shared__ float slab[4][16][DIM];                 // 32 KB
    const int tid = threadIdx.x;
    const int dout = tid & 127;
    const int h = tid >> 7;            // 0..3, wave-uniform
    const int ihalf = h & 1;
    const int base = blockIdx.x * 16;

    // stage v transposed: group h stages rows [4h, 4h+4)
    #pragma unroll
    for (int rr = 0; rr < 4; ++rr) {
        int row = base + h * 4 + rr;
        int x = q[row] + NUM_C * r[row];
        vbufT[dout][h * 4 + rr] = Ev[(size_t)x * DIM + dout];
    }

    // bulk weight preload: 64 floats/thread, all in flight at once
    const float* W = (h >= 2) ? Wa : We;
    float wreg[64];
    #pragma unroll
    for (int j = 0; j < 64; ++j)
        wreg[j] = W[(ihalf * 64 + j) * DIM + dout];

    __syncthreads();   // vbufT ready

    float acc[16];
    #pragma unroll
    for (int rr = 0; rr < 16; ++rr) acc[rr] = 0.f;

    #pragma unroll
    for (int j = 0; j < 64; ++j) {     // FULL unroll: wreg[j] compile-time
        const int i = ihalf * 64 + j;
        const float4* vp = reinterpret_cast<const float4*>(&vbufT[i][0]);
        float4 v0 = vp[0], v1 = vp[1], v2 = vp[2], v3 = vp[3];
        float vr[16] = {v0.x, v0.y, v0.z, v0.w, v1.x, v1.y, v1.z, v1.w,
                        v2.x, v2.y, v2.z, v2.w, v3.x, v3.y, v3.z, v3.w};
        float wv = wreg[j];
        #pragma unroll
        for (int rr = 0; rr < 16; ++rr)
            acc[rr] = fmaf(vr[rr], wv, acc[rr]);
    }

    #pragma unroll
    for (int rr = 0; rr < 16; ++rr) slab[h][rr][dout] = acc[rr];
    __syncthreads();

    if (h == 0) {          // e = sigmoid(We-halves + be)
        float bev = be[dout];
        #pragma unroll
        for (int rr = 0; rr < 16; ++rr) {
            int row = base + rr;
            float s = slab[0][rr][dout] + slab[1][rr][dout] + bev;
            e_out[(size_t)row * DIM + dout] = sigmoidf_fast(s);
        }
    } else if (h == 1) {   // a = tanh(Wa-halves + ba)
        float bav = ba[dout];
        #pragma unroll
        for (int rr = 0; rr < 16; ++rr) {
            int row = base + rr;
            float s = slab[2][rr][dout] + slab[3][rr][dout] + bav;
            a_out[(size_t)row * DIM + dout] = tanhf_fast(s);
        }
    }
}

// ---------------------------------------------------------------------------
// Kernel C: all-register scan, 2x TLP. Grid (g=4, ds=2, b=64) = 512 blocks.
// 256 threads: p = tid&3 (4 lanes per d, 4 m each), d = ds*64 + (tid>>2).
// e/a: 16-step register tiles double-buffered; w: depth-8 float4 ring.
// ---------------------------------------------------------------------------
__device__ __forceinline__ void kc_load_tile(const float* ep, const float* ap,
                                             int c, float (&eR)[16], float (&aR)[16]) {
    if (c < LL / 16) {
        #pragma unroll
        for (int u = 0; u < 16; ++u) {
            eR[u] = ep[(size_t)(c * 16 + u) * DIM];
            aR[u] = ap[(size_t)(c * 16 + u) * DIM];
        }
    }
}

__device__ __forceinline__ void kc_scan_tile(int c, int p, float (&Mv)[4],
                                             const float (&eR)[16], const float (&aR)[16],
                                             float4 (&wR)[8],
                                             const float* wp, float* pr) {
    #pragma unroll
    for (int u = 0; u < 16; ++u) {
        const int t = c * 16 + u;
        const int slot = u & 7;
        float4 w4 = wR[slot];
        if (t + 8 < LL)
            wR[slot] = *reinterpret_cast<const float4*>(wp + (size_t)(t + 8) * MM);
        float e_c = eR[u], a_c = aR[u];
        float wv[4] = {w4.x, w4.y, w4.z, w4.w};
        float part = 0.f;
        #pragma unroll
        for (int j = 0; j < 4; ++j) {
            float old = Mv[j];
            part = fmaf(wv[j], old, part);             // read BEFORE update
            Mv[j] = fmaf(wv[j], fmaf(-old, e_c, a_c), old);
        }
        part += quad_swap1(part);
        part += quad_swap2(part);
        if (p == 0) pr[(size_t)t * DIM] = part;
    }
}

__global__ __launch_bounds__(256) void kC(const float* __restrict__ Mv0,
                                          const float* __restrict__ w_in,
                                          const float* __restrict__ e_in,
                                          const float* __restrict__ a_in,
                                          float* __restrict__ partial) {
    const int tid = threadIdx.x;
    const int p = tid & 3;
    const int dl = tid >> 2;
    const int g = blockIdx.x, ds = blockIdx.y, b = blockIdx.z;
    const int d = ds * 64 + dl;
    const int m0 = g * 16 + p * 4;

    float Mv[4];
    #pragma unroll
    for (int j = 0; j < 4; ++j)
        Mv[j] = Mv0[(m0 + j) * DIM + d];

    const float* wp = w_in + (size_t)b * LL * MM + m0;
    const float* ep = e_in + (size_t)b * LL * DIM + d;
    const float* ap = a_in + (size_t)b * LL * DIM + d;
    float* pr = partial + ((size_t)(g * BB + b) * LL) * DIM + d;

    float eR0[16], aR0[16], eR1[16], aR1[16];
    float4 wR[8];

    kc_load_tile(ep, ap, 0, eR0, aR0);
    #pragma unroll
    for (int u = 0; u < 8; ++u)
        wR[u] = *reinterpret_cast<const float4*>(wp + (size_t)u * MM);

    for (int c = 0; c < LL / 16; c += 2) {
        kc_load_tile(ep, ap, c + 1, eR1, aR1);
        kc_scan_tile(c, p, Mv, eR0, aR0, wR, wp, pr);
        kc_load_tile(ep, ap, c + 2, eR0, aR0);
        kc_scan_tile(c + 1, p, Mv, eR1, aR1, wR, wp, pr);
    }
}

// ---------------------------------------------------------------------------
// Kernel D: read = sum_g partial; f = tanh([read,k]@Wf + bf); p = sigmoid(f@Wp+bp)
// 512 threads, 16 rows/block. Group h owns i-quarter; Wf slice in registers
// (fully-unrolled loop). Epilogue: shuffle-reduce (no bank conflicts).
// ---------------------------------------------------------------------------
__global__ __launch_bounds__(512) void kD(const int* __restrict__ q,
                                          const float* __restrict__ Ek,
                                          const float* __restrict__ Wf,
                                          const float* __restrict__ bfv,
                                          const float* __restrict__ Wp,
                                          const float* __restrict__ bp,
                                          const float* __restrict__ partial,
                                          float* __restrict__ out) {
    __shared__ __align__(16) float xbufT[2 * DIM][20];  // 20 KB
    __shared__ float slab[4][16][DIM];                  // 32 KB
    __shared__ float sred[16][2];
    const int tid = threadIdx.x;
    const int dout = tid & 127;
    const int h = tid >> 7;            // 0..3, wave-uniform
    const int base = blockIdx.x * 16;

    // stage x = [read | k] transposed: group h stages rows [4h, 4h+4)
    #pragma unroll
    for (int rr = 0; rr < 4; ++rr) {
        int row = base + h * 4 + rr;
        float rd = 0.f;
        #pragma unroll
        for (int g = 0; g < 4; ++g)
            rd += partial[(size_t)g * NROWS * DIM + (size_t)row * DIM + dout];
        xbufT[dout][h * 4 + rr] = rd;
        xbufT[DIM + dout][h * 4 + rr] = Ek[(size_t)q[row] * DIM + dout];
    }

    // bulk weight preload: 64 floats/thread (i-quarter)
    float wreg[64];
    #pragma unroll
    for (int j = 0; j < 64; ++j)
        wreg[j] = Wf[(h * 64 + j) * DIM + dout];

    __syncthreads();   // xbufT ready

    float facc[16];
    #pragma unroll
    for (int rr = 0; rr < 16; ++rr) facc[rr] = 0.f;

    #pragma unroll
    for (int j = 0; j < 64; ++j) {     // FULL unroll: wreg[j] compile-time
        const int i = h * 64 + j;
        const float4* xp = reinterpret_cast<const float4*>(&xbufT[i][0]);
        float4 x0 = xp[0], x1 = xp[1], x2 = xp[2], x3 = xp[3];
        float xr[16] = {x0.x, x0.y, x0.z, x0.w, x1.x, x1.y, x1.z, x1.w,
                        x2.x, x2.y, x2.z, x2.w, x3.x, x3.y, x3.z, x3.w};
        float wv = wreg[j];
        #pragma unroll
        for (int rr = 0; rr < 16; ++rr)
            facc[rr] = fmaf(xr[rr], wv, facc[rr]);
    }

    #pragma unroll
    for (int rr = 0; rr < 16; ++rr) slab[h][rr][dout] = facc[rr];
    __syncthreads();

    if (h == 0) {   // finish f, dot with Wp via shuffle-reduce (2 waves)
        float bfs = bfv[dout];
        float wpv = Wp[dout];
        const int lane = tid & 63;
        const int wv2 = tid >> 6;     // 0 or 1 within group 0
        #pragma unroll
        for (int rr = 0; rr < 16; ++rr) {
            float fsum = slab[0][rr][dout] + slab[1][rr][dout]
                       + slab[2][rr][dout] + slab[3][rr][dout] + bfs;
            float t = tanhf_fast(fsum) * wpv;
            #pragma unroll
            for (int o = 32; o >= 1; o >>= 1) t += __shfl_xor(t, o);
            if (lane == 0) sred[rr][wv2] = t;
        }
    }
    __syncthreads();
    if (tid < 16)
        out[base + tid] = sigmoidf_fast(sred[tid][0] + sred[tid][1] + bp[0]);
}

// ---------------------------------------------------------------------------
extern "C" void kernel_launch(void* const* d_in, const int* in_sizes, int n_in,
                              void* d_out, int out_size, void* d_ws, size_t ws_size,
                              hipStream_t stream) {
    const int*   q   = (const int*)d_in[0];
    const int*   r   = (const int*)d_in[1];
    const float* Ek  = (const float*)d_in[2];
    const float* Ev  = (const float*)d_in[3];
    const float* Mk  = (const float*)d_in[4];
    const float* Mv0 = (const float*)d_in[5];
    const float* We  = (const float*)d_in[6];
    const float* be  = (const float*)d_in[7];
    const float* Wa  = (const float*)d_in[8];
    const float* ba  = (const float*)d_in[9];
    const float* Wf  = (const float*)d_in[10];
    const float* bfv = (const float*)d_in[11];
    const float* Wp  = (const float*)d_in[12];
    const float* bp  = (const float*)d_in[13];
    float* out = (float*)d_out;

    float* ws    = (float*)d_ws;
    float* w_buf = ws;                                   // 8 MB
    float* e_buf = w_buf + (size_t)NROWS * MM;           // 16 MB
    float* a_buf = e_buf + (size_t)NROWS * DIM;          // 16 MB
    float* part  = a_buf + (size_t)NROWS * DIM;          // 4 x 16 MB

    kA<<<dim3(NROWS / 16), 256, 0, stream>>>(q, Ek, Mk, w_buf);
    kB<<<dim3(NROWS / 16), 512, 0, stream>>>(q, r, Ev, We, be, Wa, ba, e_buf, a_buf);
    kC<<<dim3(4, 2, BB), 256, 0, stream>>>(Mv0, w_buf, e_buf, a_buf, part);
    kD<<<dim3(NROWS / 16), 512, 0, stream>>>(q, Ek, Wf, bfv, Wp, bp, part, out);
}

// Round 9
// 226.229 us; speedup vs baseline: 1.9022x; 1.2157x over previous
//
#include <hip/hip_runtime.h>
#include <hip/hip_bf16.h>

#define NUM_C 1000
#define DIM   128
#define MM    64
#define BB    64
#define LL    512
#define NROWS (BB * LL)   // 32768

typedef unsigned short u16;
typedef unsigned int   u32;
typedef short bfrag __attribute__((ext_vector_type(8)));   // 8 bf16 (4 VGPRs)
typedef float f32x4 __attribute__((ext_vector_type(4)));   // MFMA acc

__device__ __forceinline__ float sigmoidf_fast(float x) { return 1.f / (1.f + __expf(-x)); }
__device__ __forceinline__ float tanhf_fast(float x) { return 1.f - 2.f / (__expf(2.f * x) + 1.f); }

__device__ __forceinline__ u16 f2bf(float x) {            // RNE f32->bf16 bits
    u32 u = __float_as_uint(x);
    return (u16)((u + 0x7FFFu + ((u >> 16) & 1u)) >> 16);
}
__device__ __forceinline__ float bf2f(u16 h) { return __uint_as_float(((u32)h) << 16); }

// DPP quad_perm(1,0,3,2) / (2,3,0,1)
__device__ __forceinline__ float quad_swap1(float x) {
    return __int_as_float(__builtin_amdgcn_mov_dpp(__float_as_int(x), 0xB1, 0xF, 0xF, true));
}
__device__ __forceinline__ float quad_swap2(float x) {
    return __int_as_float(__builtin_amdgcn_mov_dpp(__float_as_int(x), 0x4E, 0xF, 0xF, true));
}
__device__ __forceinline__ float dot4(float4 a, float4 b, float acc) {
    return fmaf(a.x, b.x, fmaf(a.y, b.y, fmaf(a.z, b.z, fmaf(a.w, b.w, acc))));
}

// ---------------------------------------------------------------------------
// Prep: transposed bf16 hi/lo weights. weT[n*128+k]=We[k][n]; wfT[n*256+k]=Wf[k][n].
// ---------------------------------------------------------------------------
__global__ __launch_bounds__(256) void kP(const float* __restrict__ We,
                                          const float* __restrict__ Wa,
                                          const float* __restrict__ Wf,
                                          u16* weT_hi, u16* weT_lo,
                                          u16* waT_hi, u16* waT_lo,
                                          u16* wfT_hi, u16* wfT_lo) {
    int idx = blockIdx.x * 256 + threadIdx.x;   // 0..32767
    if (idx < 128 * 128) {
        int n = idx >> 7, k = idx & 127;
        float we = We[k * DIM + n];
        u16 h = f2bf(we);
        weT_hi[idx] = h; weT_lo[idx] = f2bf(we - bf2f(h));
        float wa = Wa[k * DIM + n];
        u16 h2 = f2bf(wa);
        waT_hi[idx] = h2; waT_lo[idx] = f2bf(wa - bf2f(h2));
    }
    {
        int n = idx >> 8, k = idx & 255;
        float wf = Wf[k * DIM + n];
        u16 h = f2bf(wf);
        wfT_hi[idx] = h; wfT_lo[idx] = f2bf(wf - bf2f(h));
    }
}

// ---------------------------------------------------------------------------
// Kernel A (unchanged): w = softmax_m(Ek[q] . Mk^T)
// ---------------------------------------------------------------------------
__global__ __launch_bounds__(256) void kA(const int* __restrict__ q,
                                          const float* __restrict__ Ek,
                                          const float* __restrict__ Mk,
                                          float* __restrict__ w_out) {
    __shared__ __align__(16) float4 Mk4[32][64];
    const int tid = threadIdx.x;
    const int lane = tid & 63;
    const int wv = tid >> 6;

    #pragma unroll
    for (int j = 0; j < 8; ++j) {
        int i4 = wv + 4 * j;
        Mk4[i4][lane] = *reinterpret_cast<const float4*>(Mk + lane * DIM + i4 * 4);
    }
    __syncthreads();

    const int rb = __builtin_amdgcn_readfirstlane(blockIdx.x * 16 + wv * 4);
    const float* k0 = Ek + (size_t)q[rb + 0] * DIM;
    const float* k1 = Ek + (size_t)q[rb + 1] * DIM;
    const float* k2 = Ek + (size_t)q[rb + 2] * DIM;
    const float* k3 = Ek + (size_t)q[rb + 3] * DIM;

    float acc[4] = {0.f, 0.f, 0.f, 0.f};
    #pragma unroll 8
    for (int i4 = 0; i4 < 32; ++i4) {
        float4 mk = Mk4[i4][lane];
        float4 a0 = *reinterpret_cast<const float4*>(k0 + i4 * 4);
        float4 a1 = *reinterpret_cast<const float4*>(k1 + i4 * 4);
        float4 a2 = *reinterpret_cast<const float4*>(k2 + i4 * 4);
        float4 a3 = *reinterpret_cast<const float4*>(k3 + i4 * 4);
        acc[0] = dot4(a0, mk, acc[0]);
        acc[1] = dot4(a1, mk, acc[1]);
        acc[2] = dot4(a2, mk, acc[2]);
        acc[3] = dot4(a3, mk, acc[3]);
    }

    #pragma unroll
    for (int rr = 0; rr < 4; ++rr) {
        float s = acc[rr];
        float mx = s;
        #pragma unroll
        for (int o = 32; o >= 1; o >>= 1) mx = fmaxf(mx, __shfl_xor(mx, o));
        float ex = __expf(s - mx);
        float sum = ex;
        #pragma unroll
        for (int o = 32; o >= 1; o >>= 1) sum += __shfl_xor(sum, o);
        w_out[(size_t)(rb + rr) * MM + lane] = ex / sum;
    }
}

// ---------------------------------------------------------------------------
// Kernel B (MFMA): e = sigmoid(v@We+be), a = tanh(v@Wa+ba)
// 64 rows/block, 256 thr = 4 waves; wave handles 2 dout-tiles of 16.
// v staged bf16 hi/lo in LDS [rt][m][136]; weights from prepped WT global.
// ---------------------------------------------------------------------------
__global__ __launch_bounds__(256) void kB(const int* __restrict__ q,
                                          const int* __restrict__ r,
                                          const float* __restrict__ Ev,
                                          const u16* __restrict__ weT_hi, const u16* __restrict__ weT_lo,
                                          const u16* __restrict__ waT_hi, const u16* __restrict__ waT_lo,
                                          const float* __restrict__ be, const float* __restrict__ ba,
                                          float* __restrict__ e_out, float* __restrict__ a_out) {
    __shared__ __align__(16) u16 vhi[4][16][136];
    __shared__ __align__(16) u16 vlo[4][16][136];
    const int tid = threadIdx.x;
    const int base = blockIdx.x * 64;

    {   // stage: thread = (row_l = tid>>2, d0 = (tid&3)*32)
        const int row_l = tid >> 2;
        const int rts = row_l >> 4, ms = row_l & 15;
        const int d0 = (tid & 3) * 32;
        const int row = base + row_l;
        const int x = q[row] + NUM_C * r[row];
        const float* src = Ev + (size_t)x * DIM + d0;
        #pragma unroll
        for (int c8 = 0; c8 < 4; ++c8) {
            float4 f0 = *reinterpret_cast<const float4*>(src + c8 * 8);
            float4 f1 = *reinterpret_cast<const float4*>(src + c8 * 8 + 4);
            float xs[8] = {f0.x, f0.y, f0.z, f0.w, f1.x, f1.y, f1.z, f1.w};
            bfrag h, l;
            #pragma unroll
            for (int j = 0; j < 8; ++j) {
                u16 hb = f2bf(xs[j]);
                h[j] = (short)hb;
                l[j] = (short)f2bf(xs[j] - bf2f(hb));
            }
            *reinterpret_cast<bfrag*>(&vhi[rts][ms][d0 + c8 * 8]) = h;
            *reinterpret_cast<bfrag*>(&vlo[rts][ms][d0 + c8 * 8]) = l;
        }
    }
    __syncthreads();

    const int lane = tid & 63;
    const int wv = tid >> 6;
    const int nloc = lane & 15;
    const int quad = lane >> 4;

    #pragma unroll
    for (int dt = 0; dt < 2; ++dt) {
        const int n = (wv * 2 + dt) * 16 + nloc;
        bfrag Beh[4], Bel[4], Bah[4], Bal[4];
        #pragma unroll
        for (int kc = 0; kc < 4; ++kc) {
            const int ko = kc * 32 + quad * 8;
            Beh[kc] = *reinterpret_cast<const bfrag*>(weT_hi + n * DIM + ko);
            Bel[kc] = *reinterpret_cast<const bfrag*>(weT_lo + n * DIM + ko);
            Bah[kc] = *reinterpret_cast<const bfrag*>(waT_hi + n * DIM + ko);
            Bal[kc] = *reinterpret_cast<const bfrag*>(waT_lo + n * DIM + ko);
        }
        f32x4 acc_e[4], acc_a[4];
        #pragma unroll
        for (int t = 0; t < 4; ++t) { acc_e[t] = 0.f; acc_a[t] = 0.f; }

        #pragma unroll
        for (int rt = 0; rt < 4; ++rt) {
            bfrag Ah[4], Al[4];
            #pragma unroll
            for (int kc = 0; kc < 4; ++kc) {
                const int ko = kc * 32 + quad * 8;
                Ah[kc] = *reinterpret_cast<const bfrag*>(&vhi[rt][nloc][ko]);
                Al[kc] = *reinterpret_cast<const bfrag*>(&vlo[rt][nloc][ko]);
            }
            #pragma unroll
            for (int kc = 0; kc < 4; ++kc) {
                acc_e[rt] = __builtin_amdgcn_mfma_f32_16x16x32_bf16(Ah[kc], Beh[kc], acc_e[rt], 0, 0, 0);
                acc_a[rt] = __builtin_amdgcn_mfma_f32_16x16x32_bf16(Ah[kc], Bah[kc], acc_a[rt], 0, 0, 0);
                acc_e[rt] = __builtin_amdgcn_mfma_f32_16x16x32_bf16(Ah[kc], Bel[kc], acc_e[rt], 0, 0, 0);
                acc_a[rt] = __builtin_amdgcn_mfma_f32_16x16x32_bf16(Ah[kc], Bal[kc], acc_a[rt], 0, 0, 0);
                acc_e[rt] = __builtin_amdgcn_mfma_f32_16x16x32_bf16(Al[kc], Beh[kc], acc_e[rt], 0, 0, 0);
                acc_a[rt] = __builtin_amdgcn_mfma_f32_16x16x32_bf16(Al[kc], Bah[kc], acc_a[rt], 0, 0, 0);
            }
        }
        const float bev = be[n], bav = ba[n];
        #pragma unroll
        for (int rt = 0; rt < 4; ++rt) {
            #pragma unroll
            for (int rg = 0; rg < 4; ++rg) {
                const int row = base + rt * 16 + quad * 4 + rg;   // C/D: row=quad*4+reg
                e_out[(size_t)row * DIM + n] = sigmoidf_fast(acc_e[rt][rg] + bev);
                a_out[(size_t)row * DIM + n] = tanhf_fast(acc_a[rt][rg] + bav);
            }
        }
    }
}

// ---------------------------------------------------------------------------
// Kernel C (unchanged): all-register scan, grid (4,2,64).
// ---------------------------------------------------------------------------
__device__ __forceinline__ void kc_load_tile(const float* ep, const float* ap,
                                             int c, float (&eR)[16], float (&aR)[16]) {
    if (c < LL / 16) {
        #pragma unroll
        for (int u = 0; u < 16; ++u) {
            eR[u] = ep[(size_t)(c * 16 + u) * DIM];
            aR[u] = ap[(size_t)(c * 16 + u) * DIM];
        }
    }
}

__device__ __forceinline__ void kc_scan_tile(int c, int p, float (&Mv)[4],
                                             const float (&eR)[16], const float (&aR)[16],
                                             float4 (&wR)[8],
                                             const float* wp, float* pr) {
    #pragma unroll
    for (int u = 0; u < 16; ++u) {
        const int t = c * 16 + u;
        const int slot = u & 7;
        float4 w4 = wR[slot];
        if (t + 8 < LL)
            wR[slot] = *reinterpret_cast<const float4*>(wp + (size_t)(t + 8) * MM);
        float e_c = eR[u], a_c = aR[u];
        float wv[4] = {w4.x, w4.y, w4.z, w4.w};
        float part = 0.f;
        #pragma unroll
        for (int j = 0; j < 4; ++j) {
            float old = Mv[j];
            part = fmaf(wv[j], old, part);
            Mv[j] = fmaf(wv[j], fmaf(-old, e_c, a_c), old);
        }
        part += quad_swap1(part);
        part += quad_swap2(part);
        if (p == 0) pr[(size_t)t * DIM] = part;
    }
}

__global__ __launch_bounds__(256) void kC(const float* __restrict__ Mv0,
                                          const float* __restrict__ w_in,
                                          const float* __restrict__ e_in,
                                          const float* __restrict__ a_in,
                                          float* __restrict__ partial) {
    const int tid = threadIdx.x;
    const int p = tid & 3;
    const int dl = tid >> 2;
    const int g = blockIdx.x, ds = blockIdx.y, b = blockIdx.z;
    const int d = ds * 64 + dl;
    const int m0 = g * 16 + p * 4;

    float Mv[4];
    #pragma unroll
    for (int j = 0; j < 4; ++j)
        Mv[j] = Mv0[(m0 + j) * DIM + d];

    const float* wp = w_in + (size_t)b * LL * MM + m0;
    const float* ep = e_in + (size_t)b * LL * DIM + d;
    const float* ap = a_in + (size_t)b * LL * DIM + d;
    float* pr = partial + ((size_t)(g * BB + b) * LL) * DIM + d;

    float eR0[16], aR0[16], eR1[16], aR1[16];
    float4 wR[8];

    kc_load_tile(ep, ap, 0, eR0, aR0);
    #pragma unroll
    for (int u = 0; u < 8; ++u)
        wR[u] = *reinterpret_cast<const float4*>(wp + (size_t)u * MM);

    for (int c = 0; c < LL / 16; c += 2) {
        kc_load_tile(ep, ap, c + 1, eR1, aR1);
        kc_scan_tile(c, p, Mv, eR0, aR0, wR, wp, pr);
        kc_load_tile(ep, ap, c + 2, eR0, aR0);
        kc_scan_tile(c + 1, p, Mv, eR1, aR1, wR, wp, pr);
    }
}

// ---------------------------------------------------------------------------
// Kernel D (MFMA): read = sum_g partial; f = tanh([read,k]@Wf+bf);
// p = sigmoid(f@Wp+bp). 64 rows/block, K=256. fbuf overlays staging LDS.
// ---------------------------------------------------------------------------
__global__ __launch_bounds__(256) void kD(const int* __restrict__ q,
                                          const float* __restrict__ Ek,
                                          const u16* __restrict__ wfT_hi, const u16* __restrict__ wfT_lo,
                                          const float* __restrict__ bfv,
                                          const float* __restrict__ Wp, const float* __restrict__ bp,
                                          const float* __restrict__ partial,
                                          float* __restrict__ out) {
    __shared__ __align__(16) u16 xhi[4][16][264];
    __shared__ __align__(16) u16 xlo[4][16][264];
    __shared__ float sred[64][4];
    const int tid = threadIdx.x;
    const int base = blockIdx.x * 64;
    const int row_l = tid >> 2;
    const int rts = row_l >> 4, ms = row_l & 15;
    const int d0 = (tid & 3) * 32;
    const int row = base + row_l;

    // phase A: x[:, 0:128) = sum_g partial
    #pragma unroll
    for (int c8 = 0; c8 < 4; ++c8) {
        float xs[8] = {0, 0, 0, 0, 0, 0, 0, 0};
        #pragma unroll
        for (int g = 0; g < 4; ++g) {
            const float* pp = partial + ((size_t)g * NROWS + row) * DIM + d0 + c8 * 8;
            float4 t0 = *reinterpret_cast<const float4*>(pp);
            float4 t1 = *reinterpret_cast<const float4*>(pp + 4);
            xs[0] += t0.x; xs[1] += t0.y; xs[2] += t0.z; xs[3] += t0.w;
            xs[4] += t1.x; xs[5] += t1.y; xs[6] += t1.z; xs[7] += t1.w;
        }
        bfrag h, l;
        #pragma unroll
        for (int j = 0; j < 8; ++j) {
            u16 hb = f2bf(xs[j]);
            h[j] = (short)hb;
            l[j] = (short)f2bf(xs[j] - bf2f(hb));
        }
        *reinterpret_cast<bfrag*>(&xhi[rts][ms][d0 + c8 * 8]) = h;
        *reinterpret_cast<bfrag*>(&xlo[rts][ms][d0 + c8 * 8]) = l;
    }
    // phase B: x[:, 128:256) = Ek[q[row]]
    {
        const float* src = Ek + (size_t)q[row] * DIM + d0;
        #pragma unroll
        for (int c8 = 0; c8 < 4; ++c8) {
            float4 f0 = *reinterpret_cast<const float4*>(src + c8 * 8);
            float4 f1 = *reinterpret_cast<const float4*>(src + c8 * 8 + 4);
            float xs[8] = {f0.x, f0.y, f0.z, f0.w, f1.x, f1.y, f1.z, f1.w};
            bfrag h, l;
            #pragma unroll
            for (int j = 0; j < 8; ++j) {
                u16 hb = f2bf(xs[j]);
                h[j] = (short)hb;
                l[j] = (short)f2bf(xs[j] - bf2f(hb));
            }
            *reinterpret_cast<bfrag*>(&xhi[rts][ms][128 + d0 + c8 * 8]) = h;
            *reinterpret_cast<bfrag*>(&xlo[rts][ms][128 + d0 + c8 * 8]) = l;
        }
    }
    __syncthreads();

    const int lane = tid & 63;
    const int wv = tid >> 6;
    const int nloc = lane & 15;
    const int quad = lane >> 4;
    float* fbuf = reinterpret_cast<float*>(&xhi[0][0][0]);   // 64*132 f32 overlay

    f32x4 acc[2][4];
    #pragma unroll
    for (int dt = 0; dt < 2; ++dt)
        #pragma unroll
        for (int t = 0; t < 4; ++t) acc[dt][t] = 0.f;

    #pragma unroll
    for (int dt = 0; dt < 2; ++dt) {
        const int n = (wv * 2 + dt) * 16 + nloc;
        bfrag Bh[8], Bl[8];
        #pragma unroll
        for (int kc = 0; kc < 8; ++kc) {
            const int ko = kc * 32 + quad * 8;
            Bh[kc] = *reinterpret_cast<const bfrag*>(wfT_hi + n * 256 + ko);
            Bl[kc] = *reinterpret_cast<const bfrag*>(wfT_lo + n * 256 + ko);
        }
        #pragma unroll
        for (int rt = 0; rt < 4; ++rt) {
            #pragma unroll
            for (int kc = 0; kc < 8; ++kc) {
                const int ko = kc * 32 + quad * 8;
                bfrag Ah = *reinterpret_cast<const bfrag*>(&xhi[rt][nloc][ko]);
                bfrag Al = *reinterpret_cast<const bfrag*>(&xlo[rt][nloc][ko]);
                acc[dt][rt] = __builtin_amdgcn_mfma_f32_16x16x32_bf16(Ah, Bh[kc], acc[dt][rt], 0, 0, 0);
                acc[dt][rt] = __builtin_amdgcn_mfma_f32_16x16x32_bf16(Ah, Bl[kc], acc[dt][rt], 0, 0, 0);
                acc[dt][rt] = __builtin_amdgcn_mfma_f32_16x16x32_bf16(Al, Bh[kc], acc[dt][rt], 0, 0, 0);
            }
        }
    }
    __syncthreads();   // all LDS x reads done before fbuf overlay

    #pragma unroll
    for (int dt = 0; dt < 2; ++dt) {
        const int n = (wv * 2 + dt) * 16 + nloc;
        const float bfn = bfv[n], wpn = Wp[n];
        #pragma unroll
        for (int rt = 0; rt < 4; ++rt)
            #pragma unroll
            for (int rg = 0; rg < 4; ++rg)
                fbuf[(rt * 16 + quad * 4 + rg) * 132 + n] = tanhf_fast(acc[dt][rt][rg] + bfn) * wpn;
    }
    __syncthreads();

    {
        float s = 0.f;
        const int c = tid & 3;
        #pragma unroll
        for (int k = 0; k < 32; ++k) s += fbuf[row_l * 132 + c * 32 + k];
        sred[row_l][c] = s;
    }
    __syncthreads();
    if (tid < 64)
        out[base + tid] = sigmoidf_fast(sred[tid][0] + sred[tid][1] + sred[tid][2] + sred[tid][3] + bp[0]);
}

// ---------------------------------------------------------------------------
extern "C" void kernel_launch(void* const* d_in, const int* in_sizes, int n_in,
                              void* d_out, int out_size, void* d_ws, size_t ws_size,
                              hipStream_t stream) {
    const int*   q   = (const int*)d_in[0];
    const int*   r   = (const int*)d_in[1];
    const float* Ek  = (const float*)d_in[2];
    const float* Ev  = (const float*)d_in[3];
    const float* Mk  = (const float*)d_in[4];
    const float* Mv0 = (const float*)d_in[5];
    const float* We  = (const float*)d_in[6];
    const float* be  = (const float*)d_in[7];
    const float* Wa  = (const float*)d_in[8];
    const float* ba  = (const float*)d_in[9];
    const float* Wf  = (const float*)d_in[10];
    const float* bfv = (const float*)d_in[11];
    const float* Wp  = (const float*)d_in[12];
    const float* bp  = (const float*)d_in[13];
    float* out = (float*)d_out;

    float* ws    = (float*)d_ws;
    float* w_buf = ws;                                   // 8 MB
    float* e_buf = w_buf + (size_t)NROWS * MM;           // 16 MB
    float* a_buf = e_buf + (size_t)NROWS * DIM;          // 16 MB
    float* part  = a_buf + (size_t)NROWS * DIM;          // 4 x 16 MB

    // prepped bf16 weights at the END of ws (256 KB)
    size_t prep_off = (ws_size - (size_t)262144) & ~(size_t)255;
    u16* weT_hi = (u16*)((char*)d_ws + prep_off);
    u16* weT_lo = weT_hi + 16384;
    u16* waT_hi = weT_lo + 16384;
    u16* waT_lo = waT_hi + 16384;
    u16* wfT_hi = waT_lo + 16384;
    u16* wfT_lo = wfT_hi + 32768;

    kP<<<dim3(128), 256, 0, stream>>>(We, Wa, Wf, weT_hi, weT_lo, waT_hi, waT_lo, wfT_hi, wfT_lo);
    kA<<<dim3(NROWS / 16), 256, 0, stream>>>(q, Ek, Mk, w_buf);
    kB<<<dim3(NROWS / 64), 256, 0, stream>>>(q, r, Ev, weT_hi, weT_lo, waT_hi, waT_lo,
                                             be, ba, e_buf, a_buf);
    kC<<<dim3(4, 2, BB), 256, 0, stream>>>(Mv0, w_buf, e_buf, a_buf, part);
    kD<<<dim3(NROWS / 64), 256, 0, stream>>>(q, Ek, wfT_hi, wfT_lo, bfv, Wp, bp, part, out);
}